// Round 9
// baseline (340.558 us; speedup 1.0000x reference)
//
#include <hip/hip_runtime.h>

#define IN_F 32
#define HID 64
#define N_LAYERS 3
#define BN_EPS 1e-5f

__device__ __forceinline__ unsigned short f2bf(float x) {
    unsigned u = __float_as_uint(x);
    u += 0x7fffu + ((u >> 16) & 1u);
    return (unsigned short)(u >> 16);
}
__device__ __forceinline__ float bflo(unsigned v) { return __uint_as_float(v << 16); }
__device__ __forceinline__ float bfhi(unsigned v) { return __uint_as_float(v & 0xffff0000u); }

// ---------------- CSR build ----------------
__global__ __launch_bounds__(256) void k_zero(int* cnt, int* cursor, float* statsAll, int n) {
    int i = blockIdx.x * blockDim.x + threadIdx.x;
    if (i < n) cnt[i] = 0;
    if (i == 0) *cursor = 0;
    if (i < 2 * HID * N_LAYERS) statsAll[i] = 0.0f;
}

__global__ __launch_bounds__(256) void k_hist_rank(const int* __restrict__ dst, int* cnt,
                                                   unsigned short* __restrict__ rank, int e) {
    int i = blockIdx.x * blockDim.x + threadIdx.x;
    if (i >= e) return;
    int r = atomicAdd(&cnt[dst[i]], 1);
    rank[i] = (unsigned short)r;
}

__global__ __launch_bounds__(256) void k_assign(const int* __restrict__ cnt, int* rowbeg,
                                                float* dinv, int* cursor, int n) {
    int i = blockIdx.x * blockDim.x + threadIdx.x;
    int lane = threadIdx.x & 63;
    int c = (i < n) ? cnt[i] : 0;
    int s = c;
#pragma unroll
    for (int off = 1; off < 64; off <<= 1) {
        int t = __shfl_up(s, off, 64);
        if (lane >= off) s += t;
    }
    int total = __shfl(s, 63, 64);
    int base = 0;
    if (lane == 63) base = atomicAdd(cursor, total);
    base = __shfl(base, 63, 64);
    if (i < n) {
        rowbeg[i] = base + s - c;
        dinv[i] = rsqrtf((float)(c + 1));
    }
}

__global__ __launch_bounds__(256) void k_fill(const int* __restrict__ src,
                                              const int* __restrict__ dst,
                                              const int* __restrict__ rowbeg,
                                              const unsigned short* __restrict__ rank,
                                              unsigned short* __restrict__ csr_src, int e) {
    int i = blockIdx.x * blockDim.x + threadIdx.x;
    if (i >= e) return;
    int pos = rowbeg[dst[i]] + (int)rank[i];
    csr_src[pos] = (unsigned short)src[i];
}

// ---------------- fused dense ops (weight-stationary, shuffle-broadcast) ----------------
// h = relu(x@We + be); t2b = bf16((h@Wc0 + bc0) * dinv). One wave per node.
// x row loaded coalesced (lane = in-feature), broadcast via __shfl; no LDS row buffer.
__global__ __launch_bounds__(256) void k_embed_conv(const float* __restrict__ x,
                                                    const float* __restrict__ We,
                                                    const float* __restrict__ be,
                                                    const float* __restrict__ Wc,
                                                    const float* __restrict__ bc,
                                                    const float* __restrict__ dinv,
                                                    float* __restrict__ h,
                                                    unsigned short* __restrict__ t2b, int n) {
    __shared__ float sWe[IN_F * HID];
    __shared__ float sWc[HID * HID];
    for (int i = threadIdx.x; i < IN_F * HID; i += blockDim.x) sWe[i] = We[i];
    for (int i = threadIdx.x; i < HID * HID; i += blockDim.x) sWc[i] = Wc[i];
    __syncthreads();
    int f = threadIdx.x & 63;
    int wv = threadIdx.x >> 6;
    int plane = f >> 5, fin = f & 31;
    float bef = be[f], bcf = bc[f];
    int nw = gridDim.x * 4;
    int node = blockIdx.x * 4 + wv;

    float xv = (node < n) ? x[(size_t)node * IN_F + (f & 31)] : 0.0f;
    float dv = (node < n) ? dinv[node] : 0.0f;

    while (node < n) {
        int nxt = node + nw;
        float xv_n = (nxt < n) ? x[(size_t)nxt * IN_F + (f & 31)] : 0.0f;
        float dv_n = (nxt < n) ? dinv[nxt] : 0.0f;

        float a0 = bef, a1 = 0.f, a2 = 0.f, a3 = 0.f;
#pragma unroll
        for (int k = 0; k < IN_F; k += 4) {
            a0 = fmaf(__shfl(xv, k + 0, 32), sWe[(k + 0) * HID + f], a0);
            a1 = fmaf(__shfl(xv, k + 1, 32), sWe[(k + 1) * HID + f], a1);
            a2 = fmaf(__shfl(xv, k + 2, 32), sWe[(k + 2) * HID + f], a2);
            a3 = fmaf(__shfl(xv, k + 3, 32), sWe[(k + 3) * HID + f], a3);
        }
        float hv = fmaxf((a0 + a1) + (a2 + a3), 0.0f);
        h[(size_t)node * HID + f] = hv;

        float c0 = bcf, c1 = 0.f, c2 = 0.f, c3 = 0.f;
#pragma unroll
        for (int k = 0; k < HID; k += 4) {
            c0 = fmaf(__shfl(hv, k + 0, 64), sWc[(k + 0) * HID + f], c0);
            c1 = fmaf(__shfl(hv, k + 1, 64), sWc[(k + 1) * HID + f], c1);
            c2 = fmaf(__shfl(hv, k + 2, 64), sWc[(k + 2) * HID + f], c2);
            c3 = fmaf(__shfl(hv, k + 3, 64), sWc[(k + 3) * HID + f], c3);
        }
        float t = ((c0 + c1) + (c2 + c3)) * dv;
        t2b[(size_t)plane * n * 32 + (size_t)node * 32 + fin] = f2bf(t);

        node = nxt; xv = xv_n; dv = dv_n;
    }
}

// hnew = relu(bn(agg)) + h; h = hnew; t2b = bf16((hnew@W + b) * dinv).
__global__ __launch_bounds__(256) void k_bn_conv(const float* __restrict__ agg,
                                                 const float* __restrict__ stats,
                                                 const float* __restrict__ gamma,
                                                 const float* __restrict__ beta,
                                                 const float* __restrict__ W,
                                                 const float* __restrict__ b,
                                                 const float* __restrict__ dinv,
                                                 float* __restrict__ h,
                                                 unsigned short* __restrict__ t2b, int n, float invN) {
    __shared__ float sW[HID * HID];
    for (int i = threadIdx.x; i < HID * HID; i += blockDim.x) sW[i] = W[i];
    __syncthreads();
    int f = threadIdx.x & 63;
    int wv = threadIdx.x >> 6;
    int plane = f >> 5, fin = f & 31;
    float mu = stats[f] * invN;
    float var = fmaxf(stats[HID + f] * invN - mu * mu, 0.0f);
    float scale = rsqrtf(var + BN_EPS) * gamma[f];
    float shift = beta[f];
    float bf = b[f];
    int nw = gridDim.x * 4;
    int node = blockIdx.x * 4 + wv;

    float av = 0.f, hold = 0.f, dv = 0.f;
    if (node < n) {
        size_t gid = (size_t)node * HID + f;
        av = agg[gid]; hold = h[gid]; dv = dinv[node];
    }

    while (node < n) {
        int nxt = node + nw;
        float av_n = 0.f, hold_n = 0.f, dv_n = 0.f;
        if (nxt < n) {
            size_t gid_n = (size_t)nxt * HID + f;
            av_n = agg[gid_n]; hold_n = h[gid_n]; dv_n = dinv[nxt];
        }

        float bnv = (av - mu) * scale + shift;
        float hv = fmaxf(bnv, 0.0f) + hold;
        h[(size_t)node * HID + f] = hv;

        float c0 = bf, c1 = 0.f, c2 = 0.f, c3 = 0.f;
#pragma unroll
        for (int k = 0; k < HID; k += 4) {
            c0 = fmaf(__shfl(hv, k + 0, 64), sW[(k + 0) * HID + f], c0);
            c1 = fmaf(__shfl(hv, k + 1, 64), sW[(k + 1) * HID + f], c1);
            c2 = fmaf(__shfl(hv, k + 2, 64), sW[(k + 2) * HID + f], c2);
            c3 = fmaf(__shfl(hv, k + 3, 64), sW[(k + 3) * HID + f], c3);
        }
        float t = ((c0 + c1) + (c2 + c3)) * dv;
        t2b[(size_t)plane * n * 32 + (size_t)node * 32 + fin] = f2bf(t);

        node = nxt; av = av_n; hold = hold_n; dv = dv_n;
    }
}

// one 4-lane group per node per plane; 1-D grid, plane = blockIdx.x & 1
// -> plane 0 on even XCDs, plane 1 on odd XCDs (each XCD's L2 holds ONE 3.2 MB table).
__global__ __launch_bounds__(256) void k_aggregate(const int* __restrict__ rowbeg,
                                                   const int* __restrict__ cnt,
                                                   const unsigned short* __restrict__ csr_src,
                                                   const unsigned short* __restrict__ t2b,
                                                   const float* __restrict__ dinv,
                                                   float* __restrict__ agg,
                                                   float* __restrict__ stats, int n) {
    __shared__ float lsum[HID], lsq[HID];
    if (threadIdx.x < HID) { lsum[threadIdx.x] = 0.0f; lsq[threadIdx.x] = 0.0f; }
    __syncthreads();

    const int plane = blockIdx.x & 1;
    const unsigned short* tb = t2b + (size_t)plane * n * 32;

    int l4 = threadIdx.x & 3;
    int node = (blockIdx.x >> 1) * 64 + (threadIdx.x >> 2);

    float4 r0 = make_float4(0.f, 0.f, 0.f, 0.f);
    float4 r1 = make_float4(0.f, 0.f, 0.f, 0.f);

    if (node < n) {
        int beg = rowbeg[node], end = beg + cnt[node];
        uint4 sv = ((const uint4*)(tb + (size_t)node * 32))[l4];
        float4 a0, a1;
        a0.x = bflo(sv.x); a0.y = bfhi(sv.x); a0.z = bflo(sv.y); a0.w = bfhi(sv.y);
        a1.x = bflo(sv.z); a1.y = bfhi(sv.z); a1.z = bflo(sv.w); a1.w = bfhi(sv.w);
        int j = beg;
        for (; j + 8 <= end; j += 8) {
            int s0 = csr_src[j + 0], s1 = csr_src[j + 1];
            int s2 = csr_src[j + 2], s3 = csr_src[j + 3];
            int s4 = csr_src[j + 4], s5 = csr_src[j + 5];
            int s6 = csr_src[j + 6], s7 = csr_src[j + 7];
            uint4 v0 = ((const uint4*)(tb + (size_t)s0 * 32))[l4];
            uint4 v1 = ((const uint4*)(tb + (size_t)s1 * 32))[l4];
            uint4 v2 = ((const uint4*)(tb + (size_t)s2 * 32))[l4];
            uint4 v3 = ((const uint4*)(tb + (size_t)s3 * 32))[l4];
            uint4 v4 = ((const uint4*)(tb + (size_t)s4 * 32))[l4];
            uint4 v5 = ((const uint4*)(tb + (size_t)s5 * 32))[l4];
            uint4 v6 = ((const uint4*)(tb + (size_t)s6 * 32))[l4];
            uint4 v7 = ((const uint4*)(tb + (size_t)s7 * 32))[l4];
            a0.x += bflo(v0.x) + bflo(v1.x) + bflo(v2.x) + bflo(v3.x)
                  + bflo(v4.x) + bflo(v5.x) + bflo(v6.x) + bflo(v7.x);
            a0.y += bfhi(v0.x) + bfhi(v1.x) + bfhi(v2.x) + bfhi(v3.x)
                  + bfhi(v4.x) + bfhi(v5.x) + bfhi(v6.x) + bfhi(v7.x);
            a0.z += bflo(v0.y) + bflo(v1.y) + bflo(v2.y) + bflo(v3.y)
                  + bflo(v4.y) + bflo(v5.y) + bflo(v6.y) + bflo(v7.y);
            a0.w += bfhi(v0.y) + bfhi(v1.y) + bfhi(v2.y) + bfhi(v3.y)
                  + bfhi(v4.y) + bfhi(v5.y) + bfhi(v6.y) + bfhi(v7.y);
            a1.x += bflo(v0.z) + bflo(v1.z) + bflo(v2.z) + bflo(v3.z)
                  + bflo(v4.z) + bflo(v5.z) + bflo(v6.z) + bflo(v7.z);
            a1.y += bfhi(v0.z) + bfhi(v1.z) + bfhi(v2.z) + bfhi(v3.z)
                  + bfhi(v4.z) + bfhi(v5.z) + bfhi(v6.z) + bfhi(v7.z);
            a1.z += bflo(v0.w) + bflo(v1.w) + bflo(v2.w) + bflo(v3.w)
                  + bflo(v4.w) + bflo(v5.w) + bflo(v6.w) + bflo(v7.w);
            a1.w += bfhi(v0.w) + bfhi(v1.w) + bfhi(v2.w) + bfhi(v3.w)
                  + bfhi(v4.w) + bfhi(v5.w) + bfhi(v6.w) + bfhi(v7.w);
        }
        for (; j < end; ++j) {
            int s = csr_src[j];
            uint4 v = ((const uint4*)(tb + (size_t)s * 32))[l4];
            a0.x += bflo(v.x); a0.y += bfhi(v.x); a0.z += bflo(v.y); a0.w += bfhi(v.y);
            a1.x += bflo(v.z); a1.y += bfhi(v.z); a1.z += bflo(v.w); a1.w += bfhi(v.w);
        }
        float dv = dinv[node];
        r0.x = a0.x * dv; r0.y = a0.y * dv; r0.z = a0.z * dv; r0.w = a0.w * dv;
        r1.x = a1.x * dv; r1.y = a1.y * dv; r1.z = a1.z * dv; r1.w = a1.w * dv;
        float4* ar = (float4*)(agg + (size_t)node * HID + plane * 32);
        ar[l4 * 2 + 0] = r0;
        ar[l4 * 2 + 1] = r1;
    }

    float4 q0, q1;
    q0.x = r0.x * r0.x; q0.y = r0.y * r0.y; q0.z = r0.z * r0.z; q0.w = r0.w * r0.w;
    q1.x = r1.x * r1.x; q1.y = r1.y * r1.y; q1.z = r1.z * r1.z; q1.w = r1.w * r1.w;
#pragma unroll
    for (int off = 4; off < 64; off <<= 1) {
        r0.x += __shfl_xor(r0.x, off, 64); q0.x += __shfl_xor(q0.x, off, 64);
        r0.y += __shfl_xor(r0.y, off, 64); q0.y += __shfl_xor(q0.y, off, 64);
        r0.z += __shfl_xor(r0.z, off, 64); q0.z += __shfl_xor(q0.z, off, 64);
        r0.w += __shfl_xor(r0.w, off, 64); q0.w += __shfl_xor(q0.w, off, 64);
        r1.x += __shfl_xor(r1.x, off, 64); q1.x += __shfl_xor(q1.x, off, 64);
        r1.y += __shfl_xor(r1.y, off, 64); q1.y += __shfl_xor(q1.y, off, 64);
        r1.z += __shfl_xor(r1.z, off, 64); q1.z += __shfl_xor(q1.z, off, 64);
        r1.w += __shfl_xor(r1.w, off, 64); q1.w += __shfl_xor(q1.w, off, 64);
    }
    if ((threadIdx.x & 63) < 4) {
        int f0 = plane * 32 + l4 * 8;
        atomicAdd(&lsum[f0 + 0], r0.x); atomicAdd(&lsq[f0 + 0], q0.x);
        atomicAdd(&lsum[f0 + 1], r0.y); atomicAdd(&lsq[f0 + 1], q0.y);
        atomicAdd(&lsum[f0 + 2], r0.z); atomicAdd(&lsq[f0 + 2], q0.z);
        atomicAdd(&lsum[f0 + 3], r0.w); atomicAdd(&lsq[f0 + 3], q0.w);
        atomicAdd(&lsum[f0 + 4], r1.x); atomicAdd(&lsq[f0 + 4], q1.x);
        atomicAdd(&lsum[f0 + 5], r1.y); atomicAdd(&lsq[f0 + 5], q1.y);
        atomicAdd(&lsum[f0 + 6], r1.z); atomicAdd(&lsq[f0 + 6], q1.z);
        atomicAdd(&lsum[f0 + 7], r1.w); atomicAdd(&lsq[f0 + 7], q1.w);
    }
    __syncthreads();
    int fs = plane * 32 + (threadIdx.x & 31);
    if (threadIdx.x < 32) {
        atomicAdd(&stats[fs], lsum[fs]);
        atomicAdd(&stats[HID + fs], lsq[fs]);
    }
}

// final: h = relu(bn(agg)) + h
__global__ __launch_bounds__(256) void k_bn_apply(const float* __restrict__ agg,
                                                  const float* __restrict__ stats,
                                                  const float* __restrict__ gamma,
                                                  const float* __restrict__ beta,
                                                  float* __restrict__ h, int n, float invN) {
    int gid = blockIdx.x * blockDim.x + threadIdx.x;
    int node = gid >> 6, f = gid & 63;
    if (node >= n) return;
    float mu = stats[f] * invN;
    float var = fmaxf(stats[HID + f] * invN - mu * mu, 0.0f);
    float bn = (agg[gid] - mu) * rsqrtf(var + BN_EPS) * gamma[f] + beta[f];
    h[gid] = fmaxf(bn, 0.0f) + h[gid];
}

extern "C" void kernel_launch(void* const* d_in, const int* in_sizes, int n_in,
                              void* d_out, int out_size, void* d_ws, size_t ws_size,
                              hipStream_t stream) {
    const float* x       = (const float*)d_in[0];
    const int*   ei      = (const int*)d_in[1];
    const float* W_embed = (const float*)d_in[2];
    const float* b_embed = (const float*)d_in[3];
    const float* W_convs = (const float*)d_in[4];
    const float* b_convs = (const float*)d_in[5];
    const float* gamma   = (const float*)d_in[6];
    const float* beta    = (const float*)d_in[7];
    float* h = (float*)d_out;

    const int n = in_sizes[0] / IN_F;   // 50000
    const int e = in_sizes[1] / 2;      // 800000
    const int* src = ei;
    const int* dst = ei + e;

    unsigned short* t2b = (unsigned short*)d_ws;            // 2 planes * n*32 bf16
    float* agg      = (float*)(t2b + (size_t)n * HID);      // n*HID f32
    float* dinv     = agg + (size_t)n * HID;                // n
    float* statsAll = dinv + n;                             // 3*128
    int*   rowbeg   = (int*)(statsAll + 2 * HID * N_LAYERS);// n
    int*   cnt      = rowbeg + n;                           // n
    int*   cursor   = cnt + n;                              // 1
    unsigned short* csr_src = (unsigned short*)(cursor + 1);// e
    unsigned short* rank    = csr_src + e;                  // e

    const int nodeBlocks  = (n + 255) / 256;
    const int nfBlocks    = (n * HID + 255) / 256;
    const int edgeBlocks  = (e + 255) / 256;
    const int aggBlocks   = ((n + 63) / 64) * 2;   // 1-D: plane = bid&1 (XCD parity)
    const int embedBlocks = 1536;
    const int convBlocks  = 2048;

    k_zero<<<nodeBlocks, 256, 0, stream>>>(cnt, cursor, statsAll, n);
    k_hist_rank<<<edgeBlocks, 256, 0, stream>>>(dst, cnt, rank, e);
    k_assign<<<nodeBlocks, 256, 0, stream>>>(cnt, rowbeg, dinv, cursor, n);
    k_fill<<<edgeBlocks, 256, 0, stream>>>(src, dst, rowbeg, rank, csr_src, e);

    const float invN = 1.0f / (float)n;

    k_embed_conv<<<embedBlocks, 256, 0, stream>>>(x, W_embed, b_embed, W_convs, b_convs,
                                                  dinv, h, t2b, n);

    for (int l = 0; l < N_LAYERS; ++l) {
        float* stats = statsAll + (size_t)l * 2 * HID;
        k_aggregate<<<aggBlocks, 256, 0, stream>>>(rowbeg, cnt, csr_src, t2b, dinv,
                                                   agg, stats, n);
        if (l < N_LAYERS - 1) {
            const float* Wl = W_convs + (size_t)(l + 1) * HID * HID;
            const float* bl = b_convs + (size_t)(l + 1) * HID;
            k_bn_conv<<<convBlocks, 256, 0, stream>>>(agg, stats, gamma, beta, Wl, bl, dinv,
                                                      h, t2b, n, invN);
        } else {
            k_bn_apply<<<nfBlocks, 256, 0, stream>>>(agg, stats, gamma, beta, h, n, invN);
        }
    }
}